// Round 3
// baseline (336.113 us; speedup 1.0000x reference)
//
#include <hip/hip_runtime.h>

#define BB    8
#define LQN   2048
#define LKVN  2048
#define DQ    128
#define DVN   128
#define QT    16            // Q rows per block
#define KVW   32            // KV columns owned per wave per iteration
#define KTI   128           // KV per block iteration (4 waves x 32)
#define NT    (LKVN / KTI)  // 16 iterations
#define OSTR  132           // osum row stride (f32, padded)

typedef short short8 __attribute__((ext_vector_type(8)));
typedef float f32x4  __attribute__((ext_vector_type(4)));
typedef int   int4v  __attribute__((ext_vector_type(4)));

__device__ __forceinline__ short f2bf(float f) {
  unsigned u = __builtin_bit_cast(unsigned, f);
  u += 0x7fffu + ((u >> 16) & 1u);   // round-to-nearest-even
  return (short)(u >> 16);
}

__device__ __forceinline__ int packbf(float a, float b) {
  unsigned lo = (unsigned short)f2bf(a);
  unsigned hi = (unsigned short)f2bf(b);
  return (int)(lo | (hi << 16));
}

// Fused preprocessing, one launch:
//   blocks [0,512):    V (B,LKV,DV) fp32 -> Vt (B,DV,LKV) bf16
//   blocks [512,1536): K fp32 -> bf16 flat copy
__global__ __launch_bounds__(256) void pre_kernel(const float* __restrict__ K,
                                                  const float* __restrict__ V,
                                                  short* __restrict__ Kb,
                                                  short* __restrict__ Vt) {
  __shared__ float tile[128][33];
  if (blockIdx.x >= 512) {
    int i = (blockIdx.x - 512) * 256 + threadIdx.x;   // 262144 threads x 8 elems
    size_t off = (size_t)i * 8;
    float4 a = *(const float4*)(K + off);
    float4 c = *(const float4*)(K + off + 4);
    short8 o;
    o[0] = f2bf(a.x); o[1] = f2bf(a.y); o[2] = f2bf(a.z); o[3] = f2bf(a.w);
    o[4] = f2bf(c.x); o[5] = f2bf(c.y); o[6] = f2bf(c.z); o[7] = f2bf(c.w);
    *(short8*)(Kb + off) = o;
    return;
  }
  const int bx  = blockIdx.x;
  const int kv0 = (bx & 15) * 128;
  const int dv0 = ((bx >> 4) & 3) * 32;
  const int b   = bx >> 6;
  const int tid = threadIdx.x;
  const float* src = V + ((size_t)b * LKVN + kv0) * DVN + dv0;
#pragma unroll
  for (int it = 0; it < 4; ++it) {
    int idx = it * 256 + tid;
    int r = idx >> 3, c4 = idx & 7;
    float4 v = *(const float4*)(src + (size_t)r * DVN + c4 * 4);
    tile[r][c4 * 4 + 0] = v.x;
    tile[r][c4 * 4 + 1] = v.y;
    tile[r][c4 * 4 + 2] = v.z;
    tile[r][c4 * 4 + 3] = v.w;
  }
  __syncthreads();
  short* dst = Vt + ((size_t)b * DVN + dv0) * LKVN + kv0;
#pragma unroll
  for (int it = 0; it < 2; ++it) {
    int idx = it * 256 + tid;
    int row = idx >> 4, ch = idx & 15;
    short8 o;
#pragma unroll
    for (int j = 0; j < 8; ++j) o[j] = f2bf(tile[ch * 8 + j][row]);
    *(short8*)(dst + (size_t)row * LKVN + ch * 8) = o;
  }
}

// Barrier-free two-sweep attention, QT=16, 1024 blocks (4/CU, 16 waves/CU).
// Swapped MFMA: S^T = mfma(A=K, B=Q) -> lane holds P^T[kv = 16*t2 + qd*4+r][q = n].
// Wave w owns kv slice [w*32, w*32+32) of each 128-KV iteration.
// Phase 1: per-q sums of exp(s), ping-pong K prefetch. Phase 2: recompute S,
// write W float4, shfl-permute P^T into the PV B-frag, O^T = mfma(V^T, P^T).
// P2 pipelining: kA reloaded in-place (WAR) right after S-MFMAs; V loads issued
// ~300cy ahead of PV under the exp/shfl section. Only 3 barriers per block.
// blockIdx.x & 7 = batch -> XCD-pinned (K/V bf16 ~1 MB stays in one L2).
#define P1_BODY(kc, kn, t)                                                          \
  {                                                                                 \
    if ((t) + 1 < NT) {                                                             \
      _Pragma("unroll")                                                             \
      for (int t2 = 0; t2 < 2; ++t2)                                                \
        _Pragma("unroll")                                                           \
        for (int ks = 0; ks < 4; ++ks)                                              \
          kn[t2 * 4 + ks] =                                                         \
              *(const short8*)(Kw + ((size_t)(((t) + 1) * KTI + t2 * 16)) * DQ + ks * 32); \
    }                                                                               \
    _Pragma("unroll")                                                               \
    for (int t2 = 0; t2 < 2; ++t2) {                                                \
      f32x4 acc = {0.f, 0.f, 0.f, 0.f};                                             \
      _Pragma("unroll")                                                             \
      for (int ks = 0; ks < 4; ++ks)                                                \
        acc = __builtin_amdgcn_mfma_f32_16x16x32_bf16(kc[t2 * 4 + ks], qf[ks], acc, 0, 0, 0); \
      _Pragma("unroll")                                                             \
      for (int r = 0; r < 4; ++r) l_part += __expf(acc[r] * scale);                 \
    }                                                                               \
  }

__global__ __launch_bounds__(256, 4) void attn_kernel(const float* __restrict__ Q,
                                                      const short* __restrict__ Kb,
                                                      const short* __restrict__ Vt,
                                                      float* __restrict__ W,
                                                      float* __restrict__ O) {
  __shared__ __align__(16) float osum[2][QT][OSTR];   // 16.9 KB
  __shared__ float red_l[4][QT];

  const int tid  = threadIdx.x;
  const int w    = tid >> 6;
  const int lane = tid & 63;
  const int n    = lane & 15;
  const int qd   = lane >> 4;
  const int b    = blockIdx.x & 7;           // batch -> XCD
  const int q0   = (blockIdx.x >> 3) * QT;

  const short* Kw = Kb + ((size_t)b * LKVN + w * KVW + n) * DQ + qd * 8;
  const short* Vw = Vt + ((size_t)b * DVN + n) * LKVN + w * KVW + qd * 8;
  float* Wrow = W + ((size_t)b * LQN + q0 + n) * LKVN + w * KVW + qd * 4;

  // Q B-fragments straight from fp32 (per-block one-shot)
  short8 qf[4];
  {
    const float* Qrow = Q + ((size_t)b * LQN + q0 + n) * DQ + qd * 8;
#pragma unroll
    for (int ks = 0; ks < 4; ++ks) {
      float4 f0 = *(const float4*)(Qrow + ks * 32);
      float4 f1 = *(const float4*)(Qrow + ks * 32 + 4);
      short8 o;
      o[0] = f2bf(f0.x); o[1] = f2bf(f0.y); o[2] = f2bf(f0.z); o[3] = f2bf(f0.w);
      o[4] = f2bf(f1.x); o[5] = f2bf(f1.y); o[6] = f2bf(f1.z); o[7] = f2bf(f1.w);
      qf[ks] = o;
    }
  }

  const float scale = 0.08838834764831845f;  // 1/sqrt(128)
  float l_part = 0.f;

  // ---------------- phase 1: per-q row sums of exp(s), no barriers ----------------
  short8 kA[8], kB[8];
#pragma unroll
  for (int t2 = 0; t2 < 2; ++t2)
#pragma unroll
    for (int ks = 0; ks < 4; ++ks)
      kA[t2 * 4 + ks] = *(const short8*)(Kw + ((size_t)(t2 * 16)) * DQ + ks * 32);

  for (int t = 0; t < NT; t += 2) {
    P1_BODY(kA, kB, t)
    P1_BODY(kB, kA, t + 1)
  }

  // reduce l over qd groups (same q lives in lanes n, n+16, n+32, n+48)
  l_part += __shfl_xor(l_part, 16, 64);
  l_part += __shfl_xor(l_part, 32, 64);
  if (lane < 16) red_l[w][lane] = l_part;
  __syncthreads();
  const float rinv = 1.0f / (red_l[0][n] + red_l[1][n] + red_l[2][n] + red_l[3][n]);

  // ---------------- phase 2: W write + PV, no barriers ----------------
  const int srcA = n + ((qd & 1) << 5);   // lane holding kv sub-block 2*(qd&1)
  const int srcB = srcA + 16;             // lane holding kv sub-block 2*(qd&1)+1
  const int sel  = qd >> 1;               // which 16-kv half (t2) this lane consumes

  f32x4 oacc[8];
#pragma unroll
  for (int dvg = 0; dvg < 8; ++dvg) oacc[dvg] = (f32x4){0.f, 0.f, 0.f, 0.f};

  // reload K tile 0 (kA was consumed by phase 1)
#pragma unroll
  for (int t2 = 0; t2 < 2; ++t2)
#pragma unroll
    for (int ks = 0; ks < 4; ++ks)
      kA[t2 * 4 + ks] = *(const short8*)(Kw + ((size_t)(t2 * 16)) * DQ + ks * 32);

  for (int t = 0; t < NT; ++t) {
    // S^T for this tile
    f32x4 acc[2];
    __builtin_amdgcn_s_setprio(1);
#pragma unroll
    for (int t2 = 0; t2 < 2; ++t2) {
      acc[t2] = (f32x4){0.f, 0.f, 0.f, 0.f};
#pragma unroll
      for (int ks = 0; ks < 4; ++ks)
        acc[t2] = __builtin_amdgcn_mfma_f32_16x16x32_bf16(kA[t2 * 4 + ks], qf[ks], acc[t2], 0, 0, 0);
    }
    __builtin_amdgcn_s_setprio(0);

    // in-place K prefetch for t+1 (WAR over the MFMAs just issued)
    if (t + 1 < NT) {
#pragma unroll
      for (int t2 = 0; t2 < 2; ++t2)
#pragma unroll
        for (int ks = 0; ks < 4; ++ks)
          kA[t2 * 4 + ks] =
              *(const short8*)(Kw + ((size_t)((t + 1) * KTI + t2 * 16)) * DQ + ks * 32);
    }
    // V loads for the CURRENT tile — ~300cy of exp/shfl below hides L2 latency
    short8 vf[8];
#pragma unroll
    for (int dvg = 0; dvg < 8; ++dvg)
      vf[dvg] = *(const short8*)(Vw + (size_t)(dvg * 16) * LKVN + t * KTI);

    int pk[2][2];
#pragma unroll
    for (int t2 = 0; t2 < 2; ++t2) {
      float p0 = __expf(acc[t2][0] * scale) * rinv;
      float p1 = __expf(acc[t2][1] * scale) * rinv;
      float p2 = __expf(acc[t2][2] * scale) * rinv;
      float p3 = __expf(acc[t2][3] * scale) * rinv;
      f32x4 st = {p0, p1, p2, p3};
      *(f32x4*)(Wrow + t * KTI + t2 * 16) = st;
      pk[t2][0] = packbf(p0, p1);
      pk[t2][1] = packbf(p2, p3);
    }
    int a0 = __shfl(pk[0][0], srcA, 64);
    int b0 = __shfl(pk[1][0], srcA, 64);
    int a1 = __shfl(pk[0][1], srcA, 64);
    int b1 = __shfl(pk[1][1], srcA, 64);
    int a2 = __shfl(pk[0][0], srcB, 64);
    int b2 = __shfl(pk[1][0], srcB, 64);
    int a3 = __shfl(pk[0][1], srcB, 64);
    int b3 = __shfl(pk[1][1], srcB, 64);
    int4v bi;
    bi[0] = sel ? b0 : a0;
    bi[1] = sel ? b1 : a1;
    bi[2] = sel ? b2 : a2;
    bi[3] = sel ? b3 : a3;
    short8 bfr = __builtin_bit_cast(short8, bi);

    __builtin_amdgcn_s_setprio(1);
#pragma unroll
    for (int dvg = 0; dvg < 8; ++dvg)
      oacc[dvg] = __builtin_amdgcn_mfma_f32_16x16x32_bf16(vf[dvg], bfr, oacc[dvg], 0, 0, 0);
    __builtin_amdgcn_s_setprio(0);
  }

  // ---------------- cross-wave O reduction (once per block) ----------------
  if (w < 2) {
#pragma unroll
    for (int dvg = 0; dvg < 8; ++dvg)
      *(f32x4*)&osum[w][n][dvg * 16 + qd * 4] = oacc[dvg];
  }
  __syncthreads();
  if (w >= 2) {
#pragma unroll
    for (int dvg = 0; dvg < 8; ++dvg) {
      f32x4* p = (f32x4*)&osum[w - 2][n][dvg * 16 + qd * 4];
      *p = *p + oacc[dvg];
    }
  }
  __syncthreads();

  float* Ob = O + ((size_t)b * LQN + q0) * DVN;
  const int qq = tid >> 4;        // 16 q rows, 16 threads each
  const int c0 = (tid & 15) * 8;  // 8 dv per thread
#pragma unroll
  for (int c = 0; c < 2; ++c) {
    f32x4 s0 = *(const f32x4*)&osum[0][qq][c0 + c * 4];
    f32x4 s1 = *(const f32x4*)&osum[1][qq][c0 + c * 4];
    s0 = s0 + s1;
    *(f32x4*)(Ob + (size_t)qq * DVN + c0 + c * 4) = s0;
  }
}

extern "C" void kernel_launch(void* const* d_in, const int* in_sizes, int n_in,
                              void* d_out, int out_size, void* d_ws, size_t ws_size,
                              hipStream_t stream) {
  const float* Q = (const float*)d_in[0];
  const float* K = (const float*)d_in[1];
  const float* V = (const float*)d_in[2];
  float* W = (float*)d_out;                        // (B, LQ, LKV)
  float* O = W + (size_t)BB * LQN * LKVN;          // (B, LQ, DV)
  short* Kb = (short*)d_ws;                        // 4 MB bf16 (B, LKV, D)
  short* Vt = Kb + (size_t)BB * LKVN * DQ;         // 4 MB bf16 (B, DV, LKV)

  pre_kernel<<<1536, 256, 0, stream>>>(K, V, Kb, Vt);
  attn_kernel<<<1024, 256, 0, stream>>>(Q, Kb, Vt, W, O);
}

// Round 4
// 312.210 us; speedup vs baseline: 1.0766x; 1.0766x over previous
//
#include <hip/hip_runtime.h>

#define BB    8
#define LQN   2048
#define LKVN  2048
#define DQ    128
#define DVN   128
#define QT    16            // Q rows per block
#define KVW   32            // KV columns owned per wave per iteration
#define KTI   128           // KV per block iteration (4 waves x 32)
#define NT    (LKVN / KTI)  // 16 iterations
#define OSTR  132           // osum row stride (f32, padded)

typedef short short8 __attribute__((ext_vector_type(8)));
typedef float f32x4  __attribute__((ext_vector_type(4)));
typedef int   int4v  __attribute__((ext_vector_type(4)));

__device__ __forceinline__ short f2bf(float f) {
  unsigned u = __builtin_bit_cast(unsigned, f);
  u += 0x7fffu + ((u >> 16) & 1u);   // round-to-nearest-even
  return (short)(u >> 16);
}

__device__ __forceinline__ int packbf(float a, float b) {
  unsigned lo = (unsigned short)f2bf(a);
  unsigned hi = (unsigned short)f2bf(b);
  return (int)(lo | (hi << 16));
}

// Fused preprocessing, one launch:
//   blocks [0,512):    V (B,LKV,DV) fp32 -> Vt (B,DV,LKV) bf16
//   blocks [512,1536): K fp32 -> bf16 flat copy
__global__ __launch_bounds__(256) void pre_kernel(const float* __restrict__ K,
                                                  const float* __restrict__ V,
                                                  short* __restrict__ Kb,
                                                  short* __restrict__ Vt) {
  __shared__ float tile[128][33];
  if (blockIdx.x >= 512) {
    int i = (blockIdx.x - 512) * 256 + threadIdx.x;   // 262144 threads x 8 elems
    size_t off = (size_t)i * 8;
    float4 a = *(const float4*)(K + off);
    float4 c = *(const float4*)(K + off + 4);
    short8 o;
    o[0] = f2bf(a.x); o[1] = f2bf(a.y); o[2] = f2bf(a.z); o[3] = f2bf(a.w);
    o[4] = f2bf(c.x); o[5] = f2bf(c.y); o[6] = f2bf(c.z); o[7] = f2bf(c.w);
    *(short8*)(Kb + off) = o;
    return;
  }
  const int bx  = blockIdx.x;
  const int kv0 = (bx & 15) * 128;
  const int dv0 = ((bx >> 4) & 3) * 32;
  const int b   = bx >> 6;
  const int tid = threadIdx.x;
  const float* src = V + ((size_t)b * LKVN + kv0) * DVN + dv0;
#pragma unroll
  for (int it = 0; it < 4; ++it) {
    int idx = it * 256 + tid;
    int r = idx >> 3, c4 = idx & 7;
    float4 v = *(const float4*)(src + (size_t)r * DVN + c4 * 4);
    tile[r][c4 * 4 + 0] = v.x;
    tile[r][c4 * 4 + 1] = v.y;
    tile[r][c4 * 4 + 2] = v.z;
    tile[r][c4 * 4 + 3] = v.w;
  }
  __syncthreads();
  short* dst = Vt + ((size_t)b * DVN + dv0) * LKVN + kv0;
#pragma unroll
  for (int it = 0; it < 2; ++it) {
    int idx = it * 256 + tid;
    int row = idx >> 4, ch = idx & 15;
    short8 o;
#pragma unroll
    for (int j = 0; j < 8; ++j) o[j] = f2bf(tile[ch * 8 + j][row]);
    *(short8*)(dst + (size_t)row * LKVN + ch * 8) = o;
  }
}

// Barrier-free two-sweep attention, QT=16, 1024 blocks.
// __launch_bounds__(256,3): VGPR cap ~170 under either arg interpretation
// (waves/EU or blocks/CU) — fits the ~140-reg phase-2 live set WITHOUT spill
// (R3's (256,4) forced a 64-VGPR budget -> scratch traffic, 2x regression).
// Swapped MFMA: S^T = mfma(A=K, B=Q) -> lane holds P^T[kv = 16*t2 + qd*4+r][q = n].
// Wave w owns kv slice [w*32, w*32+32) of each 128-KV iteration.
// Phase 1: per-q sums of exp(s), ping-pong K prefetch. Phase 2: recompute S,
// write W float4, shfl-permute P^T into the PV B-frag, O^T = mfma(V^T, P^T).
// P2 pipelining: V loads issue first (consumed ~100cy later, this iter's PV),
// then kA in-place WAR reload for t+1 (consumed ~400cy later). 3 barriers total.
// blockIdx.x & 7 = batch -> XCD-pinned (K/V bf16 ~1 MB stays in one L2).
#define P1_BODY(kc, kn, t)                                                          \
  {                                                                                 \
    if ((t) + 1 < NT) {                                                             \
      _Pragma("unroll")                                                             \
      for (int t2 = 0; t2 < 2; ++t2)                                                \
        _Pragma("unroll")                                                           \
        for (int ks = 0; ks < 4; ++ks)                                              \
          kn[t2 * 4 + ks] =                                                         \
              *(const short8*)(Kw + ((size_t)(((t) + 1) * KTI + t2 * 16)) * DQ + ks * 32); \
    }                                                                               \
    _Pragma("unroll")                                                               \
    for (int t2 = 0; t2 < 2; ++t2) {                                                \
      f32x4 acc = {0.f, 0.f, 0.f, 0.f};                                             \
      _Pragma("unroll")                                                             \
      for (int ks = 0; ks < 4; ++ks)                                                \
        acc = __builtin_amdgcn_mfma_f32_16x16x32_bf16(kc[t2 * 4 + ks], qf[ks], acc, 0, 0, 0); \
      _Pragma("unroll")                                                             \
      for (int r = 0; r < 4; ++r) l_part += __expf(acc[r] * scale);                 \
    }                                                                               \
  }

__global__ __launch_bounds__(256, 3) void attn_kernel(const float* __restrict__ Q,
                                                      const short* __restrict__ Kb,
                                                      const short* __restrict__ Vt,
                                                      float* __restrict__ W,
                                                      float* __restrict__ O) {
  __shared__ __align__(16) float osum[2][QT][OSTR];   // 16.9 KB
  __shared__ float red_l[4][QT];

  const int tid  = threadIdx.x;
  const int w    = tid >> 6;
  const int lane = tid & 63;
  const int n    = lane & 15;
  const int qd   = lane >> 4;
  const int b    = blockIdx.x & 7;           // batch -> XCD
  const int q0   = (blockIdx.x >> 3) * QT;

  const short* Kw = Kb + ((size_t)b * LKVN + w * KVW + n) * DQ + qd * 8;
  const short* Vw = Vt + ((size_t)b * DVN + n) * LKVN + w * KVW + qd * 8;
  float* Wrow = W + ((size_t)b * LQN + q0 + n) * LKVN + w * KVW + qd * 4;

  // Q B-fragments straight from fp32 (per-block one-shot)
  short8 qf[4];
  {
    const float* Qrow = Q + ((size_t)b * LQN + q0 + n) * DQ + qd * 8;
#pragma unroll
    for (int ks = 0; ks < 4; ++ks) {
      float4 f0 = *(const float4*)(Qrow + ks * 32);
      float4 f1 = *(const float4*)(Qrow + ks * 32 + 4);
      short8 o;
      o[0] = f2bf(f0.x); o[1] = f2bf(f0.y); o[2] = f2bf(f0.z); o[3] = f2bf(f0.w);
      o[4] = f2bf(f1.x); o[5] = f2bf(f1.y); o[6] = f2bf(f1.z); o[7] = f2bf(f1.w);
      qf[ks] = o;
    }
  }

  const float scale = 0.08838834764831845f;  // 1/sqrt(128)
  float l_part = 0.f;

  // ---------------- phase 1: per-q row sums of exp(s), no barriers ----------------
  short8 kA[8], kB[8];
#pragma unroll
  for (int t2 = 0; t2 < 2; ++t2)
#pragma unroll
    for (int ks = 0; ks < 4; ++ks)
      kA[t2 * 4 + ks] = *(const short8*)(Kw + ((size_t)(t2 * 16)) * DQ + ks * 32);

  for (int t = 0; t < NT; t += 2) {
    P1_BODY(kA, kB, t)
    P1_BODY(kB, kA, t + 1)
  }

  // reduce l over qd groups (same q lives in lanes n, n+16, n+32, n+48)
  l_part += __shfl_xor(l_part, 16, 64);
  l_part += __shfl_xor(l_part, 32, 64);
  if (lane < 16) red_l[w][lane] = l_part;
  __syncthreads();
  const float rinv = 1.0f / (red_l[0][n] + red_l[1][n] + red_l[2][n] + red_l[3][n]);

  // ---------------- phase 2: W write + PV, no barriers ----------------
  const int srcA = n + ((qd & 1) << 5);   // lane holding kv sub-block 2*(qd&1)
  const int srcB = srcA + 16;             // lane holding kv sub-block 2*(qd&1)+1
  const int sel  = qd >> 1;               // which 16-kv half (t2) this lane consumes

  f32x4 oacc[8];
#pragma unroll
  for (int dvg = 0; dvg < 8; ++dvg) oacc[dvg] = (f32x4){0.f, 0.f, 0.f, 0.f};

  // reload K tile 0 (kA was consumed by phase 1)
#pragma unroll
  for (int t2 = 0; t2 < 2; ++t2)
#pragma unroll
    for (int ks = 0; ks < 4; ++ks)
      kA[t2 * 4 + ks] = *(const short8*)(Kw + ((size_t)(t2 * 16)) * DQ + ks * 32);

  for (int t = 0; t < NT; ++t) {
    // S^T for this tile
    f32x4 acc[2];
    __builtin_amdgcn_s_setprio(1);
#pragma unroll
    for (int t2 = 0; t2 < 2; ++t2) {
      acc[t2] = (f32x4){0.f, 0.f, 0.f, 0.f};
#pragma unroll
      for (int ks = 0; ks < 4; ++ks)
        acc[t2] = __builtin_amdgcn_mfma_f32_16x16x32_bf16(kA[t2 * 4 + ks], qf[ks], acc[t2], 0, 0, 0);
    }
    __builtin_amdgcn_s_setprio(0);

    // V loads for the CURRENT tile — consumed by PV after the exp/shfl section
    short8 vf[8];
#pragma unroll
    for (int dvg = 0; dvg < 8; ++dvg)
      vf[dvg] = *(const short8*)(Vw + (size_t)(dvg * 16) * LKVN + t * KTI);

    // in-place K prefetch for t+1 (WAR over the MFMAs just issued)
    if (t + 1 < NT) {
#pragma unroll
      for (int t2 = 0; t2 < 2; ++t2)
#pragma unroll
        for (int ks = 0; ks < 4; ++ks)
          kA[t2 * 4 + ks] =
              *(const short8*)(Kw + ((size_t)((t + 1) * KTI + t2 * 16)) * DQ + ks * 32);
    }

    int pk[2][2];
#pragma unroll
    for (int t2 = 0; t2 < 2; ++t2) {
      float p0 = __expf(acc[t2][0] * scale) * rinv;
      float p1 = __expf(acc[t2][1] * scale) * rinv;
      float p2 = __expf(acc[t2][2] * scale) * rinv;
      float p3 = __expf(acc[t2][3] * scale) * rinv;
      f32x4 st = {p0, p1, p2, p3};
      *(f32x4*)(Wrow + t * KTI + t2 * 16) = st;
      pk[t2][0] = packbf(p0, p1);
      pk[t2][1] = packbf(p2, p3);
    }
    int a0 = __shfl(pk[0][0], srcA, 64);
    int b0 = __shfl(pk[1][0], srcA, 64);
    int a1 = __shfl(pk[0][1], srcA, 64);
    int b1 = __shfl(pk[1][1], srcA, 64);
    int a2 = __shfl(pk[0][0], srcB, 64);
    int b2 = __shfl(pk[1][0], srcB, 64);
    int a3 = __shfl(pk[0][1], srcB, 64);
    int b3 = __shfl(pk[1][1], srcB, 64);
    int4v bi;
    bi[0] = sel ? b0 : a0;
    bi[1] = sel ? b1 : a1;
    bi[2] = sel ? b2 : a2;
    bi[3] = sel ? b3 : a3;
    short8 bfr = __builtin_bit_cast(short8, bi);

    __builtin_amdgcn_s_setprio(1);
#pragma unroll
    for (int dvg = 0; dvg < 8; ++dvg)
      oacc[dvg] = __builtin_amdgcn_mfma_f32_16x16x32_bf16(vf[dvg], bfr, oacc[dvg], 0, 0, 0);
    __builtin_amdgcn_s_setprio(0);
  }

  // ---------------- cross-wave O reduction (once per block) ----------------
  if (w < 2) {
#pragma unroll
    for (int dvg = 0; dvg < 8; ++dvg)
      *(f32x4*)&osum[w][n][dvg * 16 + qd * 4] = oacc[dvg];
  }
  __syncthreads();
  if (w >= 2) {
#pragma unroll
    for (int dvg = 0; dvg < 8; ++dvg) {
      f32x4* p = (f32x4*)&osum[w - 2][n][dvg * 16 + qd * 4];
      *p = *p + oacc[dvg];
    }
  }
  __syncthreads();

  float* Ob = O + ((size_t)b * LQN + q0) * DVN;
  const int qq = tid >> 4;        // 16 q rows, 16 threads each
  const int c0 = (tid & 15) * 8;  // 8 dv per thread
#pragma unroll
  for (int c = 0; c < 2; ++c) {
    f32x4 s0 = *(const f32x4*)&osum[0][qq][c0 + c * 4];
    f32x4 s1 = *(const f32x4*)&osum[1][qq][c0 + c * 4];
    s0 = s0 + s1;
    *(f32x4*)(Ob + (size_t)qq * DVN + c0 + c * 4) = s0;
  }
}

extern "C" void kernel_launch(void* const* d_in, const int* in_sizes, int n_in,
                              void* d_out, int out_size, void* d_ws, size_t ws_size,
                              hipStream_t stream) {
  const float* Q = (const float*)d_in[0];
  const float* K = (const float*)d_in[1];
  const float* V = (const float*)d_in[2];
  float* W = (float*)d_out;                        // (B, LQ, LKV)
  float* O = W + (size_t)BB * LQN * LKVN;          // (B, LQ, DV)
  short* Kb = (short*)d_ws;                        // 4 MB bf16 (B, LKV, D)
  short* Vt = Kb + (size_t)BB * LKVN * DQ;         // 4 MB bf16 (B, DV, LKV)

  pre_kernel<<<1536, 256, 0, stream>>>(K, V, Kb, Vt);
  attn_kernel<<<1024, 256, 0, stream>>>(Q, Kb, Vt, W, O);
}

// Round 6
// 251.931 us; speedup vs baseline: 1.3341x; 1.2393x over previous
//
#include <hip/hip_runtime.h>

#define BB    8
#define LQN   2048
#define LKVN  2048
#define DQ    128
#define DVN   128
#define QT    16            // Q rows per block
#define KVW   32            // KV columns owned per wave per tile
#define KTI   128           // KV per staged tile (4 waves x 32)
#define NT    (LKVN / KTI)  // 16 tiles
#define KSTR  136           // k_lds row stride (shorts): 128+8, 2-way-free b128 reads
#define OSTR  132           // osum row stride (f32)

typedef short short8 __attribute__((ext_vector_type(8)));
typedef float f32x4  __attribute__((ext_vector_type(4)));
typedef int   int4v  __attribute__((ext_vector_type(4)));

__device__ __forceinline__ short f2bf(float f) {
  unsigned u = __builtin_bit_cast(unsigned, f);
  u += 0x7fffu + ((u >> 16) & 1u);   // round-to-nearest-even
  return (short)(u >> 16);
}

__device__ __forceinline__ int packbf(float a, float b) {
  unsigned lo = (unsigned short)f2bf(a);
  unsigned hi = (unsigned short)f2bf(b);
  return (int)(lo | (hi << 16));
}

// Fused preprocessing, one launch:
//   blocks [0,512):    V (B,LKV,DV) fp32 -> Vt (B,DV,LKV) bf16
//   blocks [512,1536): K fp32 -> bf16 flat copy
__global__ __launch_bounds__(256) void pre_kernel(const float* __restrict__ K,
                                                  const float* __restrict__ V,
                                                  short* __restrict__ Kb,
                                                  short* __restrict__ Vt) {
  __shared__ float tile[128][33];
  if (blockIdx.x >= 512) {
    int i = (blockIdx.x - 512) * 256 + threadIdx.x;   // 262144 threads x 8 elems
    size_t off = (size_t)i * 8;
    float4 a = *(const float4*)(K + off);
    float4 c = *(const float4*)(K + off + 4);
    short8 o;
    o[0] = f2bf(a.x); o[1] = f2bf(a.y); o[2] = f2bf(a.z); o[3] = f2bf(a.w);
    o[4] = f2bf(c.x); o[5] = f2bf(c.y); o[6] = f2bf(c.z); o[7] = f2bf(c.w);
    *(short8*)(Kb + off) = o;
    return;
  }
  const int bx  = blockIdx.x;
  const int kv0 = (bx & 15) * 128;
  const int dv0 = ((bx >> 4) & 3) * 32;
  const int b   = bx >> 6;
  const int tid = threadIdx.x;
  const float* src = V + ((size_t)b * LKVN + kv0) * DVN + dv0;
#pragma unroll
  for (int it = 0; it < 4; ++it) {
    int idx = it * 256 + tid;
    int r = idx >> 3, c4 = idx & 7;
    float4 v = *(const float4*)(src + (size_t)r * DVN + c4 * 4);
    tile[r][c4 * 4 + 0] = v.x;
    tile[r][c4 * 4 + 1] = v.y;
    tile[r][c4 * 4 + 2] = v.z;
    tile[r][c4 * 4 + 3] = v.w;
  }
  __syncthreads();
  short* dst = Vt + ((size_t)b * DVN + dv0) * LKVN + kv0;
#pragma unroll
  for (int it = 0; it < 2; ++it) {
    int idx = it * 256 + tid;
    int row = idx >> 4, ch = idx & 15;
    short8 o;
#pragma unroll
    for (int j = 0; j < 8; ++j) o[j] = f2bf(tile[ch * 8 + j][row]);
    *(short8*)(dst + (size_t)row * LKVN + ch * 8) = o;
  }
}

// LDS-pipelined two-sweep attention (R0 mechanism + verified swapped-MFMA parts).
// K staged in LDS per 128-kv tile (single buffer, register prefetch of t+1 during
// compute of t, 2 barriers/tile — R0's proven pipeline; staging regs are the ONLY
// long-lived load state, so VGPR stays low and the allocator can't collapse the
// prefetch like it did in the register-resident R1/R3/R4 designs).
// Swapped MFMA: S^T = mfma(A=K from LDS, B=Q) -> lane holds P^T[kv][q=n];
// shfl-exchange builds the PV B-frag (verbatim from 3 passing rounds); V read
// direct from L2 (R4's passing pattern; kills R0's v_lds 4-way conflicts);
// W stored as float4. osum aliases k_lds (union) -> 35 KB LDS, 3 blocks/CU.
__global__ __launch_bounds__(256, 3) void attn_kernel(const float* __restrict__ Q,
                                                      const short* __restrict__ Kb,
                                                      const short* __restrict__ Vt,
                                                      float* __restrict__ W,
                                                      float* __restrict__ O) {
  __shared__ __align__(16) char smem[KTI * KSTR * 2];   // 34816 B: k_lds / osum union
  __shared__ float red_l[4][QT];
  short (*k_lds)[KSTR] = (short (*)[KSTR])smem;                 // [128][136]
  float (*osum)[QT][OSTR] = (float (*)[QT][OSTR])smem;          // [2][16][132]

  const int tid  = threadIdx.x;
  const int w    = tid >> 6;
  const int lane = tid & 63;
  const int n    = lane & 15;
  const int qd   = lane >> 4;
  const int b    = blockIdx.x & 7;           // batch -> XCD
  const int q0   = (blockIdx.x >> 3) * QT;

  const short* Kbase = Kb + (size_t)b * LKVN * DQ;
  const short* Vw = Vt + ((size_t)b * DVN + n) * LKVN + w * KVW + qd * 8;
  float* Wrow = W + ((size_t)b * LQN + q0 + n) * LKVN + w * KVW + qd * 4;

  // K staging map: load j covers rows [j*16, j*16+16), 16B chunk (tid&15) of each
  // row -> per-instruction 4 KB fully-coalesced global read; LDS write 2-way free.
  const int sr = tid >> 4;          // 0..15: row within 16-row group
  const int sc = (tid & 15) * 8;    // short offset within row (16B granule)

  // Q B-fragments straight from fp32 (per-block one-shot)
  short8 qf[4];
  {
    const float* Qrow = Q + ((size_t)b * LQN + q0 + n) * DQ + qd * 8;
#pragma unroll
    for (int ks = 0; ks < 4; ++ks) {
      float4 f0 = *(const float4*)(Qrow + ks * 32);
      float4 f1 = *(const float4*)(Qrow + ks * 32 + 4);
      short8 o;
      o[0] = f2bf(f0.x); o[1] = f2bf(f0.y); o[2] = f2bf(f0.z); o[3] = f2bf(f0.w);
      o[4] = f2bf(f1.x); o[5] = f2bf(f1.y); o[6] = f2bf(f1.z); o[7] = f2bf(f1.w);
      qf[ks] = o;
    }
  }

  const float scale = 0.08838834764831845f;  // 1/sqrt(128)
  float l_part = 0.f;
  short8 kreg[8];

  // ---------------- phase 1: per-q row sums of exp(s) ----------------
#pragma unroll
  for (int j = 0; j < 8; ++j)
    kreg[j] = *(const short8*)(Kbase + (size_t)(j * 16 + sr) * DQ + sc);
#pragma unroll
  for (int j = 0; j < 8; ++j)
    *(short8*)&k_lds[j * 16 + sr][sc] = kreg[j];

  for (int t = 0; t < NT; ++t) {
    __syncthreads();                       // staged tile visible
    if (t + 1 < NT) {                      // prefetch next tile into regs
      const short* src = Kbase + (size_t)(t + 1) * KTI * DQ;
#pragma unroll
      for (int j = 0; j < 8; ++j)
        kreg[j] = *(const short8*)(src + (size_t)(j * 16 + sr) * DQ + sc);
    }
#pragma unroll
    for (int t2 = 0; t2 < 2; ++t2) {
      f32x4 acc = {0.f, 0.f, 0.f, 0.f};
#pragma unroll
      for (int ks = 0; ks < 4; ++ks) {
        short8 kf = *(const short8*)&k_lds[w * KVW + t2 * 16 + n][ks * 32 + qd * 8];
        acc = __builtin_amdgcn_mfma_f32_16x16x32_bf16(kf, qf[ks], acc, 0, 0, 0);
      }
#pragma unroll
      for (int r = 0; r < 4; ++r) l_part += __expf(acc[r] * scale);
    }
    __syncthreads();                       // all waves done reading k_lds
    if (t + 1 < NT) {
#pragma unroll
      for (int j = 0; j < 8; ++j)
        *(short8*)&k_lds[j * 16 + sr][sc] = kreg[j];
    }
  }

  // reduce l over qd groups (same q lives in lanes n, n+16, n+32, n+48)
  l_part += __shfl_xor(l_part, 16, 64);
  l_part += __shfl_xor(l_part, 32, 64);
  if (lane < 16) red_l[w][lane] = l_part;
  __syncthreads();
  const float rinv = 1.0f / (red_l[0][n] + red_l[1][n] + red_l[2][n] + red_l[3][n]);

  // ---------------- phase 2: W write + PV ----------------
  const int srcA = n + ((qd & 1) << 5);   // lane holding kv sub-block 2*(qd&1)
  const int srcB = srcA + 16;             // lane holding kv sub-block 2*(qd&1)+1
  const int sel  = qd >> 1;               // which 16-kv half (t2) this lane consumes

  f32x4 oacc[8];
#pragma unroll
  for (int dvg = 0; dvg < 8; ++dvg) oacc[dvg] = (f32x4){0.f, 0.f, 0.f, 0.f};

  // restage tile 0 (phase-1 reads all complete past the reduce barrier)
#pragma unroll
  for (int j = 0; j < 8; ++j)
    kreg[j] = *(const short8*)(Kbase + (size_t)(j * 16 + sr) * DQ + sc);
#pragma unroll
  for (int j = 0; j < 8; ++j)
    *(short8*)&k_lds[j * 16 + sr][sc] = kreg[j];

  for (int t = 0; t < NT; ++t) {
    __syncthreads();                       // A: k_lds[t] visible
    // S^T for this tile
    f32x4 acc[2];
    __builtin_amdgcn_s_setprio(1);
#pragma unroll
    for (int t2 = 0; t2 < 2; ++t2) {
      acc[t2] = (f32x4){0.f, 0.f, 0.f, 0.f};
#pragma unroll
      for (int ks = 0; ks < 4; ++ks) {
        short8 kf = *(const short8*)&k_lds[w * KVW + t2 * 16 + n][ks * 32 + qd * 8];
        acc[t2] = __builtin_amdgcn_mfma_f32_16x16x32_bf16(kf, qf[ks], acc[t2], 0, 0, 0);
      }
    }
    __builtin_amdgcn_s_setprio(0);

    // K prefetch for t+1 (global -> regs; written to LDS after barrier C)
    if (t + 1 < NT) {
      const short* src = Kbase + (size_t)(t + 1) * KTI * DQ;
#pragma unroll
      for (int j = 0; j < 8; ++j)
        kreg[j] = *(const short8*)(src + (size_t)(j * 16 + sr) * DQ + sc);
    }
    // V loads for the CURRENT tile, direct from L2 — consumed after exp/shfl
    short8 vf[8];
#pragma unroll
    for (int dvg = 0; dvg < 8; ++dvg)
      vf[dvg] = *(const short8*)(Vw + (size_t)(dvg * 16) * LKVN + t * KTI);

    int pk[2][2];
#pragma unroll
    for (int t2 = 0; t2 < 2; ++t2) {
      float p0 = __expf(acc[t2][0] * scale) * rinv;
      float p1 = __expf(acc[t2][1] * scale) * rinv;
      float p2 = __expf(acc[t2][2] * scale) * rinv;
      float p3 = __expf(acc[t2][3] * scale) * rinv;
      f32x4 st = {p0, p1, p2, p3};
      *(f32x4*)(Wrow + t * KTI + t2 * 16) = st;
      pk[t2][0] = packbf(p0, p1);
      pk[t2][1] = packbf(p2, p3);
    }
    int a0 = __shfl(pk[0][0], srcA, 64);
    int b0 = __shfl(pk[1][0], srcA, 64);
    int a1 = __shfl(pk[0][1], srcA, 64);
    int b1 = __shfl(pk[1][1], srcA, 64);
    int a2 = __shfl(pk[0][0], srcB, 64);
    int b2 = __shfl(pk[1][0], srcB, 64);
    int a3 = __shfl(pk[0][1], srcB, 64);
    int b3 = __shfl(pk[1][1], srcB, 64);
    int4v bi;
    bi[0] = sel ? b0 : a0;
    bi[1] = sel ? b1 : a1;
    bi[2] = sel ? b2 : a2;
    bi[3] = sel ? b3 : a3;
    short8 bfr = __builtin_bit_cast(short8, bi);

    __builtin_amdgcn_s_setprio(1);
#pragma unroll
    for (int dvg = 0; dvg < 8; ++dvg)
      oacc[dvg] = __builtin_amdgcn_mfma_f32_16x16x32_bf16(vf[dvg], bfr, oacc[dvg], 0, 0, 0);
    __builtin_amdgcn_s_setprio(0);

    __syncthreads();                       // C: all k_lds readers done
    if (t + 1 < NT) {
#pragma unroll
      for (int j = 0; j < 8; ++j)
        *(short8*)&k_lds[j * 16 + sr][sc] = kreg[j];
    }
  }

  // ---------------- cross-wave O reduction (osum aliases k_lds; all k_lds
  // readers are past barrier C of the last tile, so the union is safe) -------
  if (w < 2) {
#pragma unroll
    for (int dvg = 0; dvg < 8; ++dvg)
      *(f32x4*)&osum[w][n][dvg * 16 + qd * 4] = oacc[dvg];
  }
  __syncthreads();
  if (w >= 2) {
#pragma unroll
    for (int dvg = 0; dvg < 8; ++dvg) {
      f32x4* p = (f32x4*)&osum[w - 2][n][dvg * 16 + qd * 4];
      *p = *p + oacc[dvg];
    }
  }
  __syncthreads();

  float* Ob = O + ((size_t)b * LQN + q0) * DVN;
  const int qq = tid >> 4;        // 16 q rows, 16 threads each
  const int c0 = (tid & 15) * 8;  // 8 dv per thread
#pragma unroll
  for (int c = 0; c < 2; ++c) {
    f32x4 s0 = *(const f32x4*)&osum[0][qq][c0 + c * 4];
    f32x4 s1 = *(const f32x4*)&osum[1][qq][c0 + c * 4];
    s0 = s0 + s1;
    *(f32x4*)(Ob + (size_t)qq * DVN + c0 + c * 4) = s0;
  }
}

extern "C" void kernel_launch(void* const* d_in, const int* in_sizes, int n_in,
                              void* d_out, int out_size, void* d_ws, size_t ws_size,
                              hipStream_t stream) {
  const float* Q = (const float*)d_in[0];
  const float* K = (const float*)d_in[1];
  const float* V = (const float*)d_in[2];
  float* W = (float*)d_out;                        // (B, LQ, LKV)
  float* O = W + (size_t)BB * LQN * LKVN;          // (B, LQ, DV)
  short* Kb = (short*)d_ws;                        // 4 MB bf16 (B, LKV, D)
  short* Vt = Kb + (size_t)BB * LKVN * DQ;         // 4 MB bf16 (B, DV, LKV)

  pre_kernel<<<1536, 256, 0, stream>>>(K, V, Kb, Vt);
  attn_kernel<<<1024, 256, 0, stream>>>(Q, Kb, Vt, W, O);
}

// Round 7
// 236.517 us; speedup vs baseline: 1.4211x; 1.0652x over previous
//
#include <hip/hip_runtime.h>

#define BB    8
#define LQN   2048
#define LKVN  2048
#define DQ    128
#define DVN   128
#define QT    32            // Q rows per block (2 groups of 16)
#define KTI   128           // KV per staged tile (4 slices x 32)
#define NT    (LKVN / KTI)  // 16 tiles
#define OSTR  132           // osum row stride (f32)

typedef short short8 __attribute__((ext_vector_type(8)));
typedef float f32x4  __attribute__((ext_vector_type(4)));
typedef int   int4v  __attribute__((ext_vector_type(4)));

__device__ __forceinline__ short f2bf(float f) {
  unsigned u = __builtin_bit_cast(unsigned, f);
  u += 0x7fffu + ((u >> 16) & 1u);   // round-to-nearest-even
  return (short)(u >> 16);
}

__device__ __forceinline__ int packbf(float a, float b) {
  unsigned lo = (unsigned short)f2bf(a);
  unsigned hi = (unsigned short)f2bf(b);
  return (int)(lo | (hi << 16));
}

// Fused preprocessing, one launch:
//   blocks [0,512):    V (B,LKV,DV) fp32 -> Vt (B,DV,LKV) bf16
//   blocks [512,1536): K fp32 -> bf16 flat copy
__global__ __launch_bounds__(256) void pre_kernel(const float* __restrict__ K,
                                                  const float* __restrict__ V,
                                                  short* __restrict__ Kb,
                                                  short* __restrict__ Vt) {
  __shared__ float tile[128][33];
  if (blockIdx.x >= 512) {
    int i = (blockIdx.x - 512) * 256 + threadIdx.x;   // 262144 threads x 8 elems
    size_t off = (size_t)i * 8;
    float4 a = *(const float4*)(K + off);
    float4 c = *(const float4*)(K + off + 4);
    short8 o;
    o[0] = f2bf(a.x); o[1] = f2bf(a.y); o[2] = f2bf(a.z); o[3] = f2bf(a.w);
    o[4] = f2bf(c.x); o[5] = f2bf(c.y); o[6] = f2bf(c.z); o[7] = f2bf(c.w);
    *(short8*)(Kb + off) = o;
    return;
  }
  const int bx  = blockIdx.x;
  const int kv0 = (bx & 15) * 128;
  const int dv0 = ((bx >> 4) & 3) * 32;
  const int b   = bx >> 6;
  const int tid = threadIdx.x;
  const float* src = V + ((size_t)b * LKVN + kv0) * DVN + dv0;
#pragma unroll
  for (int it = 0; it < 4; ++it) {
    int idx = it * 256 + tid;
    int r = idx >> 3, c4 = idx & 7;
    float4 v = *(const float4*)(src + (size_t)r * DVN + c4 * 4);
    tile[r][c4 * 4 + 0] = v.x;
    tile[r][c4 * 4 + 1] = v.y;
    tile[r][c4 * 4 + 2] = v.z;
    tile[r][c4 * 4 + 3] = v.w;
  }
  __syncthreads();
  short* dst = Vt + ((size_t)b * DVN + dv0) * LKVN + kv0;
#pragma unroll
  for (int it = 0; it < 2; ++it) {
    int idx = it * 256 + tid;
    int row = idx >> 4, ch = idx & 15;
    short8 o;
#pragma unroll
    for (int j = 0; j < 8; ++j) o[j] = f2bf(tile[ch * 8 + j][row]);
    *(short8*)(dst + (size_t)row * LKVN + ch * 8) = o;
  }
}

// 8-wave (512-thread) LDS-pipelined two-sweep attention, QT=32, grid 512.
// Wave id w -> (s = w&3: kv slice of 32, g = w>>2: q group of 16). All 8 waves
// share ONE staged 128-kv K tile (2x LDS reuse vs 4-wave blocks; K L2 traffic
// per XCD halves to ~96 MB -> ~22us L2 floor). Per-wave math identical to the
// verified R6 kernel (swapped MFMA S^T = mfma(K,Q); shfl P-exchange; V direct
// from L2; float4 W stores).
// k_lds XOR swizzle: short col c stored at c ^ ((row&7)<<3), KSTR=128. MFMA
// reads (rows s*32+t2*16+n, col ks*32+qd*8) then hit 8 distinct 16B slots per
// 8 lanes -> all 32 banks, 2 lanes/bank = conflict-free (fixes the ~8-way
// conflicts the +8-pad variants had: 5.3-7.3M cycles).
// Staging: 4 rounds x 512 threads x 16B; kreg[4] = only 16 VGPRs of load state.
// 2 barriers/tile, 2 sweeps, osum aliases k_lds after last tile.
__global__ __launch_bounds__(512, 4) void attn_kernel(const float* __restrict__ Q,
                                                      const short* __restrict__ Kb,
                                                      const short* __restrict__ Vt,
                                                      float* __restrict__ W,
                                                      float* __restrict__ O) {
  __shared__ __align__(16) char smem[33792];   // k_lds (32768B) / osum (33792B) union
  __shared__ float red_l[4][QT];
  short* k_lds = (short*)smem;                          // [128][128] swizzled
  float (*osum)[QT][OSTR] = (float (*)[QT][OSTR])smem;  // [2][32][132]

  const int tid  = threadIdx.x;
  const int w    = tid >> 6;
  const int lane = tid & 63;
  const int n    = lane & 15;
  const int qd   = lane >> 4;
  const int s    = w & 3;                    // kv slice (32 cols)
  const int g    = w >> 2;                   // q group (16 rows)
  const int b    = blockIdx.x & 7;           // batch -> XCD
  const int q0   = (blockIdx.x >> 3) * QT;

  const short* Kbase = Kb + (size_t)b * LKVN * DQ;
  const short* Vw = Vt + ((size_t)b * DVN + n) * LKVN + s * 32 + qd * 8;
  float* Wrow = W + ((size_t)b * LQN + q0 + g * 16 + n) * LKVN + s * 32 + qd * 4;

  // staging map: round j covers rows [j*32, j*32+32); thread -> (row sr, 16B chunk sc)
  const int sr = tid >> 4;          // 0..31
  const int sc = tid & 15;          // 16B chunk (8 shorts)
  const int swz_w = (sc * 8) ^ ((sr & 7) << 3);   // swizzled short-col for writes

  // MFMA-read short index for (row, short-col base) with swizzle
  const int krow = s * 32 + n;                    // + t2*16 added per use
  const int rswz = (n & 7) << 3;

  // Q B-fragments straight from fp32 (per-block one-shot)
  short8 qf[4];
  {
    const float* Qrow = Q + ((size_t)b * LQN + q0 + g * 16 + n) * DQ + qd * 8;
#pragma unroll
    for (int ks = 0; ks < 4; ++ks) {
      float4 f0 = *(const float4*)(Qrow + ks * 32);
      float4 f1 = *(const float4*)(Qrow + ks * 32 + 4);
      short8 o;
      o[0] = f2bf(f0.x); o[1] = f2bf(f0.y); o[2] = f2bf(f0.z); o[3] = f2bf(f0.w);
      o[4] = f2bf(f1.x); o[5] = f2bf(f1.y); o[6] = f2bf(f1.z); o[7] = f2bf(f1.w);
      qf[ks] = o;
    }
  }

  const float scale = 0.08838834764831845f;  // 1/sqrt(128)
  float l_part = 0.f;
  short8 kreg[4];

  // ---------------- phase 1: per-q row sums of exp(s) ----------------
#pragma unroll
  for (int j = 0; j < 4; ++j)
    kreg[j] = *(const short8*)(Kbase + (size_t)(j * 32 + sr) * DQ + sc * 8);
#pragma unroll
  for (int j = 0; j < 4; ++j)
    *(short8*)&k_lds[(j * 32 + sr) * 128 + swz_w] = kreg[j];

  for (int t = 0; t < NT; ++t) {
    __syncthreads();                       // A: staged tile visible
    if (t + 1 < NT) {                      // prefetch next tile into regs
      const short* src = Kbase + (size_t)(t + 1) * KTI * DQ;
#pragma unroll
      for (int j = 0; j < 4; ++j)
        kreg[j] = *(const short8*)(src + (size_t)(j * 32 + sr) * DQ + sc * 8);
    }
#pragma unroll
    for (int t2 = 0; t2 < 2; ++t2) {
      f32x4 acc = {0.f, 0.f, 0.f, 0.f};
#pragma unroll
      for (int ks = 0; ks < 4; ++ks) {
        short8 kf = *(const short8*)&k_lds[(krow + t2 * 16) * 128 +
                                           ((ks * 32 + qd * 8) ^ rswz)];
        acc = __builtin_amdgcn_mfma_f32_16x16x32_bf16(kf, qf[ks], acc, 0, 0, 0);
      }
#pragma unroll
      for (int r = 0; r < 4; ++r) l_part += __expf(acc[r] * scale);
    }
    __syncthreads();                       // C: all waves done reading k_lds
    if (t + 1 < NT) {
#pragma unroll
      for (int j = 0; j < 4; ++j)
        *(short8*)&k_lds[(j * 32 + sr) * 128 + swz_w] = kreg[j];
    }
  }

  // reduce l over qd groups (same q lives in lanes n, n+16, n+32, n+48)
  l_part += __shfl_xor(l_part, 16, 64);
  l_part += __shfl_xor(l_part, 32, 64);
  if (lane < 16) red_l[s][g * 16 + lane] = l_part;
  __syncthreads();
  const float rinv =
      1.0f / (red_l[0][g * 16 + n] + red_l[1][g * 16 + n] +
              red_l[2][g * 16 + n] + red_l[3][g * 16 + n]);

  // ---------------- phase 2: W write + PV ----------------
  const int srcA = n + ((qd & 1) << 5);   // lane holding kv sub-block 2*(qd&1)
  const int srcB = srcA + 16;             // lane holding kv sub-block 2*(qd&1)+1
  const int sel  = qd >> 1;               // which 16-kv half (t2) this lane consumes

  f32x4 oacc[8];
#pragma unroll
  for (int dvg = 0; dvg < 8; ++dvg) oacc[dvg] = (f32x4){0.f, 0.f, 0.f, 0.f};

  // restage tile 0 (all phase-1 k_lds reads are before the reduce barrier)
#pragma unroll
  for (int j = 0; j < 4; ++j)
    kreg[j] = *(const short8*)(Kbase + (size_t)(j * 32 + sr) * DQ + sc * 8);
#pragma unroll
  for (int j = 0; j < 4; ++j)
    *(short8*)&k_lds[(j * 32 + sr) * 128 + swz_w] = kreg[j];

  for (int t = 0; t < NT; ++t) {
    __syncthreads();                       // A: k_lds[t] visible
    f32x4 acc[2];
    __builtin_amdgcn_s_setprio(1);
#pragma unroll
    for (int t2 = 0; t2 < 2; ++t2) {
      acc[t2] = (f32x4){0.f, 0.f, 0.f, 0.f};
#pragma unroll
      for (int ks = 0; ks < 4; ++ks) {
        short8 kf = *(const short8*)&k_lds[(krow + t2 * 16) * 128 +
                                           ((ks * 32 + qd * 8) ^ rswz)];
        acc[t2] = __builtin_amdgcn_mfma_f32_16x16x32_bf16(kf, qf[ks], acc[t2], 0, 0, 0);
      }
    }
    __builtin_amdgcn_s_setprio(0);

    // K prefetch for t+1 (global -> regs; written to LDS after barrier C)
    if (t + 1 < NT) {
      const short* src = Kbase + (size_t)(t + 1) * KTI * DQ;
#pragma unroll
      for (int j = 0; j < 4; ++j)
        kreg[j] = *(const short8*)(src + (size_t)(j * 32 + sr) * DQ + sc * 8);
    }
    // V loads for the CURRENT tile, direct from L2 — consumed after exp/shfl
    short8 vf[8];
#pragma unroll
    for (int dvg = 0; dvg < 8; ++dvg)
      vf[dvg] = *(const short8*)(Vw + (size_t)(dvg * 16) * LKVN + t * KTI);

    int pk[2][2];
#pragma unroll
    for (int t2 = 0; t2 < 2; ++t2) {
      float p0 = __expf(acc[t2][0] * scale) * rinv;
      float p1 = __expf(acc[t2][1] * scale) * rinv;
      float p2 = __expf(acc[t2][2] * scale) * rinv;
      float p3 = __expf(acc[t2][3] * scale) * rinv;
      f32x4 st = {p0, p1, p2, p3};
      *(f32x4*)(Wrow + t * KTI + t2 * 16) = st;
      pk[t2][0] = packbf(p0, p1);
      pk[t2][1] = packbf(p2, p3);
    }
    int a0 = __shfl(pk[0][0], srcA, 64);
    int b0 = __shfl(pk[1][0], srcA, 64);
    int a1 = __shfl(pk[0][1], srcA, 64);
    int b1 = __shfl(pk[1][1], srcA, 64);
    int a2 = __shfl(pk[0][0], srcB, 64);
    int b2 = __shfl(pk[1][0], srcB, 64);
    int a3 = __shfl(pk[0][1], srcB, 64);
    int b3 = __shfl(pk[1][1], srcB, 64);
    int4v bi;
    bi[0] = sel ? b0 : a0;
    bi[1] = sel ? b1 : a1;
    bi[2] = sel ? b2 : a2;
    bi[3] = sel ? b3 : a3;
    short8 bfr = __builtin_bit_cast(short8, bi);

    __builtin_amdgcn_s_setprio(1);
#pragma unroll
    for (int dvg = 0; dvg < 8; ++dvg)
      oacc[dvg] = __builtin_amdgcn_mfma_f32_16x16x32_bf16(vf[dvg], bfr, oacc[dvg], 0, 0, 0);
    __builtin_amdgcn_s_setprio(0);

    __syncthreads();                       // C: all k_lds readers done
    if (t + 1 < NT) {
#pragma unroll
      for (int j = 0; j < 4; ++j)
        *(short8*)&k_lds[(j * 32 + sr) * 128 + swz_w] = kreg[j];
    }
  }

  // ---------------- cross-slice O reduction (osum aliases k_lds; all k_lds
  // readers are past barrier C of the last tile, so the union is safe) -------
  // PV C/D layout: q = g*16 + n, dv = dvg*16 + qd*4 + r. Slices 0,1 write
  // slots 0,1; slices 2,3 add into slots 0,1; final pass sums the two slots.
  if (s < 2) {
#pragma unroll
    for (int dvg = 0; dvg < 8; ++dvg)
      *(f32x4*)&osum[s][g * 16 + n][dvg * 16 + qd * 4] = oacc[dvg];
  }
  __syncthreads();
  if (s >= 2) {
#pragma unroll
    for (int dvg = 0; dvg < 8; ++dvg) {
      f32x4* p = (f32x4*)&osum[s - 2][g * 16 + n][dvg * 16 + qd * 4];
      *p = *p + oacc[dvg];
    }
  }
  __syncthreads();

  float* Ob = O + ((size_t)b * LQN + q0) * DVN;
  const int qq = tid >> 4;        // 32 q rows, 16 threads each
  const int c0 = (tid & 15) * 8;  // 8 dv per thread
#pragma unroll
  for (int c = 0; c < 2; ++c) {
    f32x4 s0 = *(const f32x4*)&osum[0][qq][c0 + c * 4];
    f32x4 s1 = *(const f32x4*)&osum[1][qq][c0 + c * 4];
    s0 = s0 + s1;
    *(f32x4*)(Ob + (size_t)qq * DVN + c0 + c * 4) = s0;
  }
}

extern "C" void kernel_launch(void* const* d_in, const int* in_sizes, int n_in,
                              void* d_out, int out_size, void* d_ws, size_t ws_size,
                              hipStream_t stream) {
  const float* Q = (const float*)d_in[0];
  const float* K = (const float*)d_in[1];
  const float* V = (const float*)d_in[2];
  float* W = (float*)d_out;                        // (B, LQ, LKV)
  float* O = W + (size_t)BB * LQN * LKVN;          // (B, LQ, DV)
  short* Kb = (short*)d_ws;                        // 4 MB bf16 (B, LKV, D)
  short* Vt = Kb + (size_t)BB * LKVN * DQ;         // 4 MB bf16 (B, DV, LKV)

  pre_kernel<<<1536, 256, 0, stream>>>(K, V, Kb, Vt);
  attn_kernel<<<512, 512, 0, stream>>>(Q, Kb, Vt, W, O);
}

// Round 8
// 232.482 us; speedup vs baseline: 1.4458x; 1.0174x over previous
//
#include <hip/hip_runtime.h>

#define BB    8
#define LQN   2048
#define LKVN  2048
#define DQ    128
#define DVN   128
#define QT    32            // Q rows per block (2 groups of 16)
#define KTI   128           // KV per staged tile (4 slices x 32)
#define NT    (LKVN / KTI)  // 16 tiles
#define OSTR  132           // osum row stride (f32)

typedef short short8 __attribute__((ext_vector_type(8)));
typedef float f32x4  __attribute__((ext_vector_type(4)));
typedef int   int4v  __attribute__((ext_vector_type(4)));

__device__ __forceinline__ short f2bf(float f) {
  unsigned u = __builtin_bit_cast(unsigned, f);
  u += 0x7fffu + ((u >> 16) & 1u);   // round-to-nearest-even
  return (short)(u >> 16);
}

__device__ __forceinline__ int packbf(float a, float b) {
  unsigned lo = (unsigned short)f2bf(a);
  unsigned hi = (unsigned short)f2bf(b);
  return (int)(lo | (hi << 16));
}

// async global->LDS DMA, 16B per lane, LDS dest = wave-uniform base + lane*16
__device__ __forceinline__ void gld_lds16(const void* g, void* l) {
  __builtin_amdgcn_global_load_lds(
      (const __attribute__((address_space(1))) unsigned int*)g,
      (__attribute__((address_space(3))) unsigned int*)l, 16, 0, 0);
}

// Fused preprocessing, one launch:
//   blocks [0,512):    V (B,LKV,DV) fp32 -> Vt (B,DV,LKV) bf16
//   blocks [512,1536): K fp32 -> bf16 flat copy
__global__ __launch_bounds__(256) void pre_kernel(const float* __restrict__ K,
                                                  const float* __restrict__ V,
                                                  short* __restrict__ Kb,
                                                  short* __restrict__ Vt) {
  __shared__ float tile[128][33];
  if (blockIdx.x >= 512) {
    int i = (blockIdx.x - 512) * 256 + threadIdx.x;   // 262144 threads x 8 elems
    size_t off = (size_t)i * 8;
    float4 a = *(const float4*)(K + off);
    float4 c = *(const float4*)(K + off + 4);
    short8 o;
    o[0] = f2bf(a.x); o[1] = f2bf(a.y); o[2] = f2bf(a.z); o[3] = f2bf(a.w);
    o[4] = f2bf(c.x); o[5] = f2bf(c.y); o[6] = f2bf(c.z); o[7] = f2bf(c.w);
    *(short8*)(Kb + off) = o;
    return;
  }
  const int bx  = blockIdx.x;
  const int kv0 = (bx & 15) * 128;
  const int dv0 = ((bx >> 4) & 3) * 32;
  const int b   = bx >> 6;
  const int tid = threadIdx.x;
  const float* src = V + ((size_t)b * LKVN + kv0) * DVN + dv0;
#pragma unroll
  for (int it = 0; it < 4; ++it) {
    int idx = it * 256 + tid;
    int r = idx >> 3, c4 = idx & 7;
    float4 v = *(const float4*)(src + (size_t)r * DVN + c4 * 4);
    tile[r][c4 * 4 + 0] = v.x;
    tile[r][c4 * 4 + 1] = v.y;
    tile[r][c4 * 4 + 2] = v.z;
    tile[r][c4 * 4 + 3] = v.w;
  }
  __syncthreads();
  short* dst = Vt + ((size_t)b * DVN + dv0) * LKVN + kv0;
#pragma unroll
  for (int it = 0; it < 2; ++it) {
    int idx = it * 256 + tid;
    int row = idx >> 4, ch = idx & 15;
    short8 o;
#pragma unroll
    for (int j = 0; j < 8; ++j) o[j] = f2bf(tile[ch * 8 + j][row]);
    *(short8*)(dst + (size_t)row * LKVN + ch * 8) = o;
  }
}

// 8-wave two-sweep attention with ASYNC double-buffered K staging (T3 minimal).
// Geometry/math identical to the verified R7 kernel: wave w -> (s=w&3 kv-slice
// of 32, g=w>>2 q-group of 16); swapped MFMA S^T = mfma(K,Q); shfl P-exchange;
// V direct from L2; float4 W stores; QT=32, grid 512 (2 blocks/CU resident).
// NEW: K tiles staged via __builtin_amdgcn_global_load_lds (width 16) into a
// 2x32KB double buffer. No staging registers (nothing for the allocator to
// sink — the R1/R3/R4 failure mode), no ds_writes, and ONE __syncthreads per
// tile: its built-in vmcnt(0) drain lands after the full ~600cy body covers
// the DMA latency. Barriers/tile: 2 -> 1.
// Swizzle preserved by PRE-SWIZZLING the global source address (m173):
// LDS[row][granule g] holds K[row][g ^ (row&7)]; reads XOR with (n&7)=row&7.
// Chunk map: chunk c = w*4+j covers rows 4c..4c+3; lane l -> row 4c+(l>>4),
// src granule (l&15) ^ (4*(c&1) + (l>>4)).
__global__ __launch_bounds__(512, 4) void attn_kernel(const float* __restrict__ Q,
                                                      const short* __restrict__ Kb,
                                                      const short* __restrict__ Vt,
                                                      float* __restrict__ W,
                                                      float* __restrict__ O) {
  __shared__ __align__(16) short k_lds[2 * 16384];      // 64 KB double buffer
  __shared__ float red_l[4][QT];
  float (*osum)[QT][OSTR] = (float (*)[QT][OSTR])k_lds; // epilogue alias (33.8KB)

  const int tid  = threadIdx.x;
  const int w    = tid >> 6;
  const int lane = tid & 63;
  const int n    = lane & 15;
  const int qd   = lane >> 4;
  const int s    = w & 3;                    // kv slice (32 cols)
  const int g    = w >> 2;                   // q group (16 rows)
  const int b    = blockIdx.x & 7;           // batch -> XCD
  const int q0   = (blockIdx.x >> 3) * QT;

  const short* Kbase = Kb + (size_t)b * LKVN * DQ;
  const short* Vw = Vt + ((size_t)b * DVN + n) * LKVN + s * 32 + qd * 8;
  float* Wrow = W + ((size_t)b * LQN + q0 + g * 16 + n) * LKVN + s * 32 + qd * 4;

  // DMA source pointers (pre-swizzled). Even/odd j differ in the XOR key bit 2.
  const int drow = lane >> 4;                // 0..3: row within 4-row chunk
  const short* KdmaE = Kbase + (size_t)(16 * w + drow) * DQ +
                       (((lane & 15) ^ drow) * 8);
  const short* KdmaO = Kbase + (size_t)(16 * w + drow) * DQ +
                       (((lane & 15) ^ (4 + drow)) * 8);
  short* ldsw = k_lds + (w * 4) * 512;       // wave's chunk base (lane off implicit)

#define STAGE(bsel, t)                                                          \
  {                                                                             \
    const short* ge = KdmaE + (size_t)(t) * KTI * DQ;                           \
    const short* go = KdmaO + (size_t)(t) * KTI * DQ;                           \
    short* lb = ldsw + (bsel) * 16384;                                          \
    gld_lds16(ge,           lb);                                                \
    gld_lds16(go + 4 * DQ,  lb + 512);                                          \
    gld_lds16(ge + 8 * DQ,  lb + 1024);                                         \
    gld_lds16(go + 12 * DQ, lb + 1536);                                         \
  }

  // MFMA-read base: row = s*32 + t2*16 + n, col = (ks*32 + qd*8) ^ ((n&7)*8)
  const int krow = (s * 32 + n) * 128;
  const int rswz = (n & 7) << 3;

  // Q B-fragments straight from fp32 (per-block one-shot)
  short8 qf[4];
  {
    const float* Qrow = Q + ((size_t)b * LQN + q0 + g * 16 + n) * DQ + qd * 8;
#pragma unroll
    for (int ks = 0; ks < 4; ++ks) {
      float4 f0 = *(const float4*)(Qrow + ks * 32);
      float4 f1 = *(const float4*)(Qrow + ks * 32 + 4);
      short8 o;
      o[0] = f2bf(f0.x); o[1] = f2bf(f0.y); o[2] = f2bf(f0.z); o[3] = f2bf(f0.w);
      o[4] = f2bf(f1.x); o[5] = f2bf(f1.y); o[6] = f2bf(f1.z); o[7] = f2bf(f1.w);
      qf[ks] = o;
    }
  }

  const float scale = 0.08838834764831845f;  // 1/sqrt(128)
  float l_part = 0.f;

  // ---------------- phase 1: per-q row sums of exp(s) ----------------
  STAGE(0, 0)
  __syncthreads();                           // tile 0 staged
  int cur = 0;
  for (int t = 0; t < NT; ++t) {
    if (t + 1 < NT) STAGE(cur ^ 1, t + 1)    // async DMA, covered by body
    const short* kb = k_lds + cur * 16384;
#pragma unroll
    for (int t2 = 0; t2 < 2; ++t2) {
      f32x4 acc = {0.f, 0.f, 0.f, 0.f};
#pragma unroll
      for (int ks = 0; ks < 4; ++ks) {
        short8 kf = *(const short8*)&kb[krow + t2 * 2048 + ((ks * 32 + qd * 8) ^ rswz)];
        acc = __builtin_amdgcn_mfma_f32_16x16x32_bf16(kf, qf[ks], acc, 0, 0, 0);
      }
#pragma unroll
      for (int r = 0; r < 4; ++r) l_part += __expf(acc[r] * scale);
    }
    __syncthreads();                         // drains my DMAs -> next buf ready
    cur ^= 1;
  }

  // reduce l over qd groups (same q lives in lanes n, n+16, n+32, n+48)
  l_part += __shfl_xor(l_part, 16, 64);
  l_part += __shfl_xor(l_part, 32, 64);
  if (lane < 16) red_l[s][g * 16 + lane] = l_part;
  STAGE(0, 0)                                // restage tile 0 under the reduce
  __syncthreads();
  const float rinv =
      1.0f / (red_l[0][g * 16 + n] + red_l[1][g * 16 + n] +
              red_l[2][g * 16 + n] + red_l[3][g * 16 + n]);

  // ---------------- phase 2: W write + PV ----------------
  const int srcA = n + ((qd & 1) << 5);   // lane holding kv sub-block 2*(qd&1)
  const int srcB = srcA + 16;             // lane holding kv sub-block 2*(qd&1)+1
  const int sel  = qd >> 1;               // which 16-kv half (t2) this lane consumes

  f32x4 oacc[8];
#pragma unroll
  for (int dvg = 0; dvg < 8; ++dvg) oacc[dvg] = (f32x4){0.f, 0.f, 0.f, 0.f};

  cur = 0;
  for (int t = 0; t < NT; ++t) {
    if (t + 1 < NT) STAGE(cur ^ 1, t + 1)
    const short* kb = k_lds + cur * 16384;
    f32x4 acc[2];
    __builtin_amdgcn_s_setprio(1);
#pragma unroll
    for (int t2 = 0; t2 < 2; ++t2) {
      acc[t2] = (f32x4){0.f, 0.f, 0.f, 0.f};
#pragma unroll
      for (int ks = 0; ks < 4; ++ks) {
        short8 kf = *(const short8*)&kb[krow + t2 * 2048 + ((ks * 32 + qd * 8) ^ rswz)];
        acc[t2] = __builtin_amdgcn_mfma_f32_16x16x32_bf16(kf, qf[ks], acc[t2], 0, 0, 0);
      }
    }
    __builtin_amdgcn_s_setprio(0);

    // V loads for the CURRENT tile, direct from L2 — consumed after exp/shfl
    short8 vf[8];
#pragma unroll
    for (int dvg = 0; dvg < 8; ++dvg)
      vf[dvg] = *(const short8*)(Vw + (size_t)(dvg * 16) * LKVN + t * KTI);

    int pk[2][2];
#pragma unroll
    for (int t2 = 0; t2 < 2; ++t2) {
      float p0 = __expf(acc[t2][0] * scale) * rinv;
      float p1 = __expf(acc[t2][1] * scale) * rinv;
      float p2 = __expf(acc[t2][2] * scale) * rinv;
      float p3 = __expf(acc[t2][3] * scale) * rinv;
      f32x4 st = {p0, p1, p2, p3};
      *(f32x4*)(Wrow + t * KTI + t2 * 16) = st;
      pk[t2][0] = packbf(p0, p1);
      pk[t2][1] = packbf(p2, p3);
    }
    int a0 = __shfl(pk[0][0], srcA, 64);
    int b0 = __shfl(pk[1][0], srcA, 64);
    int a1 = __shfl(pk[0][1], srcA, 64);
    int b1 = __shfl(pk[1][1], srcA, 64);
    int a2 = __shfl(pk[0][0], srcB, 64);
    int b2 = __shfl(pk[1][0], srcB, 64);
    int a3 = __shfl(pk[0][1], srcB, 64);
    int b3 = __shfl(pk[1][1], srcB, 64);
    int4v bi;
    bi[0] = sel ? b0 : a0;
    bi[1] = sel ? b1 : a1;
    bi[2] = sel ? b2 : a2;
    bi[3] = sel ? b3 : a3;
    short8 bfr = __builtin_bit_cast(short8, bi);

    __builtin_amdgcn_s_setprio(1);
#pragma unroll
    for (int dvg = 0; dvg < 8; ++dvg)
      oacc[dvg] = __builtin_amdgcn_mfma_f32_16x16x32_bf16(vf[dvg], bfr, oacc[dvg], 0, 0, 0);
    __builtin_amdgcn_s_setprio(0);

    __syncthreads();                         // drains my DMAs -> next buf ready
    cur ^= 1;
  }

  // ---------------- cross-slice O reduction (osum aliases k_lds; all k_lds
  // readers are past the final loop barrier, so the alias is safe) ----------
  if (s < 2) {
#pragma unroll
    for (int dvg = 0; dvg < 8; ++dvg)
      *(f32x4*)&osum[s][g * 16 + n][dvg * 16 + qd * 4] = oacc[dvg];
  }
  __syncthreads();
  if (s >= 2) {
#pragma unroll
    for (int dvg = 0; dvg < 8; ++dvg) {
      f32x4* p = (f32x4*)&osum[s - 2][g * 16 + n][dvg * 16 + qd * 4];
      *p = *p + oacc[dvg];
    }
  }
  __syncthreads();

  float* Ob = O + ((size_t)b * LQN + q0) * DVN;
  const int qq = tid >> 4;        // 32 q rows, 16 threads each
  const int c0 = (tid & 15) * 8;  // 8 dv per thread
#pragma unroll
  for (int c = 0; c < 2; ++c) {
    f32x4 s0 = *(const f32x4*)&osum[0][qq][c0 + c * 4];
    f32x4 s1 = *(const f32x4*)&osum[1][qq][c0 + c * 4];
    s0 = s0 + s1;
    *(f32x4*)(Ob + (size_t)qq * DVN + c0 + c * 4) = s0;
  }
}

extern "C" void kernel_launch(void* const* d_in, const int* in_sizes, int n_in,
                              void* d_out, int out_size, void* d_ws, size_t ws_size,
                              hipStream_t stream) {
  const float* Q = (const float*)d_in[0];
  const float* K = (const float*)d_in[1];
  const float* V = (const float*)d_in[2];
  float* W = (float*)d_out;                        // (B, LQ, LKV)
  float* O = W + (size_t)BB * LQN * LKVN;          // (B, LQ, DV)
  short* Kb = (short*)d_ws;                        // 4 MB bf16 (B, LKV, D)
  short* Vt = Kb + (size_t)BB * LKVN * DQ;         // 4 MB bf16 (B, DV, LKV)

  pre_kernel<<<1536, 256, 0, stream>>>(K, V, Kb, Vt);
  attn_kernel<<<512, 512, 0, stream>>>(Q, Kb, Vt, W, O);
}